// Round 1
// baseline (184.822 us; speedup 1.0000x reference)
//
#include <hip/hip_runtime.h>

// WeightedDiceLoss on MI355X -- round 8: barrier-free fp32 rewrite.
// Each WAVE independently owns an 8-row output band x full 512-col row.
// 31-row vertical box sum kept in registers (vr[8]); slides by loading the
// +16 row (fresh) and re-loading the -15 row (guaranteed L2 hit: 31-row
// window = 64KB/image) straight from global. No LDS ring, no bf16 pack,
// no __syncthreads in the hot loop -> latency hidden by 16 waves/CU of
// fully independent work instead of lockstepped barriers.
// input, target: (64,1,512,512) fp32. Output: scalar fp32.
// weight = 1 + 5*|box31(target) - target|; loss = 1 - (2*I+1)/(A+B+1).

#define BATCH 64
#define H     512
#define W     512
#define RB    8                        // rows per wave-task
#define BANDS (H / RB)                 // 64 bands per image
#define TASKS (BATCH * BANDS)          // 4096 wave-tasks
#define NBLK  (TASKS / 4)              // 1024 blocks (4 waves each)

__global__ __launch_bounds__(256, 4) void fused_kernel(const float* __restrict__ tgt,
                                                       const float* __restrict__ inp,
                                                       float4* __restrict__ partials) {
    const int tid  = threadIdx.x;
    const int lane = tid & 63;
    const int wv   = tid >> 6;
    const int task = blockIdx.x * 4 + wv;      // 4 consecutive bands, same image
    const int band = task & (BANDS - 1);
    const int b    = task >> 6;                // task / BANDS
    const int R0   = band * RB;
    const float* timg = tgt + (size_t)b * H * W;
    const float* iimg = inp + (size_t)b * H * W;
    const int col0 = lane * 8;                 // this lane's 8 columns

    // wave-edge masks for the horizontal 31-window (zero padding)
    const float mL1 = (lane >= 1) ? 1.f : 0.f;
    const float mR1 = (lane <= 62) ? 1.f : 0.f;
    const float mL2 = (lane >= 2) ? 1.f : 0.f;
    const float mR2 = (lane <= 61) ? 1.f : 0.f;

    // ---- init vertical sums centered at row R0 (rows R0-15 .. R0+15) ------
    float vr[8];
    #pragma unroll
    for (int k = 0; k < 8; ++k) vr[k] = 0.f;
    #pragma unroll
    for (int jj = -15; jj <= 15; ++jj) {
        const int r = R0 + jj;
        if (r >= 0 && r < H) {
            const float4 a = *(const float4*)(timg + (size_t)r * W + col0);
            const float4 c = *(const float4*)(timg + (size_t)r * W + col0 + 4);
            vr[0] += a.x; vr[1] += a.y; vr[2] += a.z; vr[3] += a.w;
            vr[4] += c.x; vr[5] += c.y; vr[6] += c.z; vr[7] += c.w;
        }
    }

    const float inv = 1.0f / 961.0f;
    float aI = 0.f, aA = 0.f, aB = 0.f;

    #pragma unroll 2
    for (int s = 0; s < RB; ++s) {
        const int h  = R0 + s;                 // this step's output row
        const int ar = h + 16;                 // row entering the window
        const int sr = h - 15;                 // row leaving the window

        // ---- issue ALL loads for this step up front (overlap with VALU) ---
        const float4 i0 = *(const float4*)(iimg + (size_t)h * W + col0);
        const float4 i1 = *(const float4*)(iimg + (size_t)h * W + col0 + 4);
        const float4 t0 = *(const float4*)(timg + (size_t)h * W + col0);
        const float4 t1 = *(const float4*)(timg + (size_t)h * W + col0 + 4);
        float4 a0 = make_float4(0.f, 0.f, 0.f, 0.f), a1 = a0;
        float4 u0 = a0, u1 = a0;
        if (ar < H) {                          // wave-uniform branch
            a0 = *(const float4*)(timg + (size_t)ar * W + col0);
            a1 = *(const float4*)(timg + (size_t)ar * W + col0 + 4);
        }
        if (sr >= 0) {                         // wave-uniform branch (L2 hit)
            u0 = *(const float4*)(timg + (size_t)sr * W + col0);
            u1 = *(const float4*)(timg + (size_t)sr * W + col0 + 4);
        }

        // ---- horizontal window from current vr (verified segment-sum) ----
        const float p1 = vr[0];
        const float p2 = p1 + vr[1];
        const float p3 = p2 + vr[2];
        const float p4 = p3 + vr[3];
        const float p5 = p4 + vr[4];
        const float p6 = p5 + vr[5];
        const float p7 = p6 + vr[6];
        const float sS = p7 + vr[7];
        const float f1 = sS - p1, f2 = sS - p2, f3 = sS - p3, f4 = sS - p4;
        const float f5 = sS - p5, f6 = sS - p6, f7 = sS - p7;

        const float sL1 = __shfl_up(sS, 1, 64);
        const float sR1 = __shfl_down(sS, 1, 64);
        const float g1 = __shfl_up(f1, 2, 64);
        const float g2 = __shfl_up(f2, 2, 64);
        const float g3 = __shfl_up(f3, 2, 64);
        const float g4 = __shfl_up(f4, 2, 64);
        const float g5 = __shfl_up(f5, 2, 64);
        const float g6 = __shfl_up(f6, 2, 64);
        const float g7 = __shfl_up(f7, 2, 64);
        const float q1 = __shfl_down(p1, 2, 64);
        const float q2 = __shfl_down(p2, 2, 64);
        const float q3 = __shfl_down(p3, 2, 64);
        const float q4 = __shfl_down(p4, 2, 64);
        const float q5 = __shfl_down(p5, 2, 64);
        const float q6 = __shfl_down(p6, 2, 64);
        const float q7 = __shfl_down(p7, 2, 64);

        const float S3 = fmaf(mL1, sL1, fmaf(mR1, sR1, sS));
        float win[8];
        win[0] = fmaf(mL2, g1, S3);
        win[1] = fmaf(mL2, g2, fmaf(mR2, q1, S3));
        win[2] = fmaf(mL2, g3, fmaf(mR2, q2, S3));
        win[3] = fmaf(mL2, g4, fmaf(mR2, q3, S3));
        win[4] = fmaf(mL2, g5, fmaf(mR2, q4, S3));
        win[5] = fmaf(mL2, g6, fmaf(mR2, q5, S3));
        win[6] = fmaf(mL2, g7, fmaf(mR2, q6, S3));
        win[7] = fmaf(mR2, q7, S3);

        const float tv[8] = {t0.x, t0.y, t0.z, t0.w, t1.x, t1.y, t1.z, t1.w};
        const float iv[8] = {i0.x, i0.y, i0.z, i0.w, i1.x, i1.y, i1.z, i1.w};

        #pragma unroll
        for (int k = 0; k < 8; ++k) {
            const float wgt = fmaf(5.0f, fabsf(fmaf(win[k], inv, -tv[k])), 1.0f);
            aI += iv[k] * tv[k] * wgt;
            aA += iv[k] * wgt;
            aB += tv[k] * wgt;
        }

        // ---- slide the vertical window: vr += row(ar) - row(sr) ----------
        vr[0] += a0.x - u0.x; vr[1] += a0.y - u0.y;
        vr[2] += a0.z - u0.z; vr[3] += a0.w - u0.w;
        vr[4] += a1.x - u1.x; vr[5] += a1.y - u1.y;
        vr[6] += a1.z - u1.z; vr[7] += a1.w - u1.w;
    }

    // ---- wave reduction (64 lanes) ----------------------------------------
    #pragma unroll
    for (int off = 32; off > 0; off >>= 1) {
        aI += __shfl_down(aI, off, 64);
        aA += __shfl_down(aA, off, 64);
        aB += __shfl_down(aB, off, 64);
    }
    // cross-wave reduction (tiny LDS; only barrier in the kernel)
    __shared__ float sm[12];
    if (lane == 0) { sm[wv] = aI; sm[4 + wv] = aA; sm[8 + wv] = aB; }
    __syncthreads();
    if (tid == 0) {
        float4 o;
        o.x = sm[0] + sm[1] + sm[2] + sm[3];
        o.y = sm[4] + sm[5] + sm[6] + sm[7];
        o.z = sm[8] + sm[9] + sm[10] + sm[11];
        o.w = 0.f;
        partials[blockIdx.x] = o;
    }
}

// ---------------------------------------------------------------------------
// Reduce NBLK (1024) partials + finalize. One block, 1024 threads (16 waves).
// ---------------------------------------------------------------------------
__global__ __launch_bounds__(1024) void reduce_kernel(const float4* __restrict__ partials,
                                                      float* __restrict__ out) {
    const int tid = threadIdx.x;
    const float4 v = partials[tid];          // exactly 1024 entries
    float aI = v.x, aA = v.y, aB = v.z;
    #pragma unroll
    for (int off = 32; off > 0; off >>= 1) {
        aI += __shfl_down(aI, off, 64);
        aA += __shfl_down(aA, off, 64);
        aB += __shfl_down(aB, off, 64);
    }
    __shared__ float s[3][16];
    const int wvx = tid >> 6, ln = tid & 63;
    if (ln == 0) { s[0][wvx] = aI; s[1][wvx] = aA; s[2][wvx] = aB; }
    __syncthreads();
    if (tid == 0) {
        float I = 0.f, A = 0.f, Bv = 0.f;
        #pragma unroll
        for (int k = 0; k < 16; ++k) { I += s[0][k]; A += s[1][k]; Bv += s[2][k]; }
        out[0] = 1.0f - (2.0f * I + 1.0f) / (A + Bv + 1.0f);
    }
}

extern "C" void kernel_launch(void* const* d_in, const int* in_sizes, int n_in,
                              void* d_out, int out_size, void* d_ws, size_t ws_size,
                              hipStream_t stream) {
    const float* inp = (const float*)d_in[0];   // "input"
    const float* tgt = (const float*)d_in[1];   // "target"
    float* out = (float*)d_out;

    // workspace: [0, NBLK*16) per-block partials (float4); written before read.
    float4* partials = (float4*)d_ws;

    fused_kernel<<<NBLK, 256, 0, stream>>>(tgt, inp, partials);
    reduce_kernel<<<1, 1024, 0, stream>>>(partials, out);
}

// Round 2
// 149.833 us; speedup vs baseline: 1.2335x; 1.2335x over previous
//
#include <hip/hip_runtime.h>
#include <hip/hip_bf16.h>

// WeightedDiceLoss on MI355X -- round 9: R7 LDS-ring structure (proven 51us,
// 98MB fetch) + software-pipelined global loads across RAW barriers.
// R8 post-mortem: caches do NOT carry the 31-row reuse window (FETCH 98->227MB)
// -> the bf16 LDS row-ring is mandatory. R7's residual stall: __syncthreads()
// drains vmcnt(0) twice per step, so the target-row prefetch gets only ~550cy
// of cover for ~900cy HBM latency. Fix (T3/T4 pattern): raw s_barrier +
// explicit lgkmcnt(0) only where the LDS publish needs visibility; global
// loads for step j+1 issue at step j and stay in flight across both barriers
// (compiler inserts counted vmcnt at first use = publish, a full step later).
// Also: incremental ring-slot arithmetic (kills 9 magic-mul `% 38` per step).
//
// input, target: (64,1,512,512) fp32. Output: scalar fp32.
// weight = 1 + 5*|box31(target) - target|; loss = 1 - (2*I+1)/(A+B+1).
//
// Ring layout: row slot = 256 u32; u32 d holds cols (2d, 2d+1) as bf16
// (low 16 = even col). Lane reads its 8 cols as ONE uint4 at dword 4*lane.

#define BATCH 64
#define H     512
#define W     512
#define PADR  15
#define RBAND 32                      // rows per block
#define RING  38                      // ring rows (live span exactly 38)
#define NBLK  (BATCH * (H / RBAND))   // 1024 blocks -> 4/CU exactly

static __device__ __forceinline__ unsigned pack2(float e, float o) {
    __hip_bfloat162 h = __float22bfloat162_rn(make_float2(e, o));
    unsigned u; __builtin_memcpy(&u, &h, 4); return u;
}
static __device__ __forceinline__ float2 unpk(unsigned u) {
    return make_float2(__uint_as_float(u << 16),
                       __uint_as_float(u & 0xffff0000u));
}
static __device__ __forceinline__ int wrap38(int s) {
    return (s >= RING) ? s - RING : s;     // valid for s in [0, 2*RING)
}

__global__ __launch_bounds__(256, 4) void fused_kernel(const float* __restrict__ tgt,
                                                       const float* __restrict__ inp,
                                                       float4* __restrict__ partials) {
    const int tid  = threadIdx.x;
    const int lane = tid & 63;
    const int wv   = tid >> 6;
    const int blk  = blockIdx.x;
    const int band = blk & 15;               // H/RBAND = 16 bands
    const int b    = blk >> 4;
    const int R0   = band * RBAND;
    const float* timg = tgt + (size_t)b * H * W;
    const float* iimg = inp + (size_t)b * H * W;

    __shared__ __align__(16) unsigned ring[RING * 256];   // 38912 B -> 4 blocks/CU

    const int col0 = lane * 8;               // this lane's 8 columns
    const int ofs  = lane * 4;               // lane's uint4 dword offset in a slot

    // ---- preload target rows R0-15 .. R0+22 (38 rows), pack to bf16 -------
    for (int k = 0; k < 10; ++k) {
        const int r_off = wv + 4 * k;
        if (r_off < RING) {
            const int row = R0 - 15 + r_off;  // max R0+22 <= 502 < H always
            float4 v0 = make_float4(0.f, 0.f, 0.f, 0.f), v1 = v0;
            if (row >= 0) {
                v0 = *(const float4*)(timg + (size_t)row * W + col0);
                v1 = *(const float4*)(timg + (size_t)row * W + col0 + 4);
            }
            uint4 u;
            u.x = pack2(v0.x, v0.y); u.y = pack2(v0.z, v0.w);
            u.z = pack2(v1.x, v1.y); u.w = pack2(v1.z, v1.w);
            *(uint4*)&ring[((row + RING) % RING) * 256 + ofs] = u;
        }
    }
    __syncthreads();

    // wave-edge masks for the horizontal window (zero padding)
    const float mL1 = (lane >= 1) ? 1.f : 0.f;
    const float mR1 = (lane <= 62) ? 1.f : 0.f;
    const float mL2 = (lane >= 2) ? 1.f : 0.f;
    const float mR2 = (lane <= 61) ? 1.f : 0.f;

    // ---- init vertical sums centered at row R0+wv (rows R0+wv-15..+15) ----
    float vr[8];
    #pragma unroll
    for (int k = 0; k < 8; ++k) vr[k] = 0.f;
    {
        int sl = (R0 + wv + 23) % RING;      // slot of row R0+wv-15
        for (int jj = 0; jj < 31; ++jj) {
            const uint4 c = *(const uint4*)&ring[sl * 256 + ofs];
            const float2 e0 = unpk(c.x), e1 = unpk(c.y), e2 = unpk(c.z), e3 = unpk(c.w);
            vr[0] += e0.x; vr[1] += e0.y; vr[2] += e1.x; vr[3] += e1.y;
            vr[4] += e2.x; vr[5] += e2.y; vr[6] += e3.x; vr[7] += e3.y;
            sl = wrap38(sl + 1);
        }
    }

    const float inv = 1.0f / 961.0f;
    float aI = 0.f, aA = 0.f, aB = 0.f;

    // ---- software-pipeline prologue: loads for step 0 ----------------------
    // prow(0) = R0+23+wv <= 506 < H always; input row R0+wv always valid.
    const int prow0 = R0 + 23 + wv;
    float4 pc0 = *(const float4*)(timg + (size_t)prow0 * W + col0);
    float4 pc1 = *(const float4*)(timg + (size_t)prow0 * W + col0 + 4);
    float4 ic0 = *(const float4*)(iimg + (size_t)(R0 + wv) * W + col0);
    float4 ic1 = *(const float4*)(iimg + (size_t)(R0 + wv) * W + col0 + 4);

    int sl_h = (R0 + wv) % RING;             // slot of this wave's current row h

    for (int j = 0; j < 8; ++j) {
        const int h = R0 + 4 * j + wv;       // this wave's output row

        // ---- issue NEXT-iteration global loads (stay in flight across the
        //      raw barriers below; consumed/published a full step later) ----
        float4 pn0 = make_float4(0.f, 0.f, 0.f, 0.f), pn1 = pn0;
        float4 in0 = pn0, in1 = pn0;
        const int prow_n = h + 27;           // prow(j+1) = R0+4(j+1)+23+wv
        if (j < 6 && prow_n < H) {
            pn0 = *(const float4*)(timg + (size_t)prow_n * W + col0);
            pn1 = *(const float4*)(timg + (size_t)prow_n * W + col0 + 4);
        }
        if (j < 7) {
            in0 = *(const float4*)(iimg + (size_t)(h + 4) * W + col0);
            in1 = *(const float4*)(iimg + (size_t)(h + 4) * W + col0 + 4);
        }

        // ---- LDS reads (incremental slot arithmetic, no modulo) -----------
        const uint4 tc = *(const uint4*)&ring[sl_h * 256 + ofs];
        uint4 ua[4], us[4];
        if (j < 7) {
            #pragma unroll
            for (int q = 0; q < 4; ++q) {
                const int ar = h + 16 + q;
                const int sa = wrap38(sl_h + 16 + q);
                ua[q] = (ar < H) ? *(const uint4*)&ring[sa * 256 + ofs]
                                 : make_uint4(0u, 0u, 0u, 0u);
                const int ss = wrap38(sl_h + 23 + q);   // row h-15+q
                us[q] = *(const uint4*)&ring[ss * 256 + ofs];
            }
        }

        // ---- horizontal window from current vr (verified segment-sum) -----
        const float p1 = vr[0];
        const float p2 = p1 + vr[1];
        const float p3 = p2 + vr[2];
        const float p4 = p3 + vr[3];
        const float p5 = p4 + vr[4];
        const float p6 = p5 + vr[5];
        const float p7 = p6 + vr[6];
        const float s  = p7 + vr[7];
        const float f1 = s - p1, f2 = s - p2, f3 = s - p3, f4 = s - p4;
        const float f5 = s - p5, f6 = s - p6, f7 = s - p7;

        const float sL1 = __shfl_up(s, 1, 64);
        const float sR1 = __shfl_down(s, 1, 64);
        const float g1 = __shfl_up(f1, 2, 64);
        const float g2 = __shfl_up(f2, 2, 64);
        const float g3 = __shfl_up(f3, 2, 64);
        const float g4 = __shfl_up(f4, 2, 64);
        const float g5 = __shfl_up(f5, 2, 64);
        const float g6 = __shfl_up(f6, 2, 64);
        const float g7 = __shfl_up(f7, 2, 64);
        const float q1 = __shfl_down(p1, 2, 64);
        const float q2 = __shfl_down(p2, 2, 64);
        const float q3 = __shfl_down(p3, 2, 64);
        const float q4 = __shfl_down(p4, 2, 64);
        const float q5 = __shfl_down(p5, 2, 64);
        const float q6 = __shfl_down(p6, 2, 64);
        const float q7 = __shfl_down(p7, 2, 64);

        const float S3 = fmaf(mL1, sL1, fmaf(mR1, sR1, s));
        float win[8];
        win[0] = fmaf(mL2, g1, S3);
        win[1] = fmaf(mL2, g2, fmaf(mR2, q1, S3));
        win[2] = fmaf(mL2, g3, fmaf(mR2, q2, S3));
        win[3] = fmaf(mL2, g4, fmaf(mR2, q3, S3));
        win[4] = fmaf(mL2, g5, fmaf(mR2, q4, S3));
        win[5] = fmaf(mL2, g6, fmaf(mR2, q5, S3));
        win[6] = fmaf(mL2, g7, fmaf(mR2, q6, S3));
        win[7] = fmaf(mR2, q7, S3);

        const float2 t0 = unpk(tc.x), t1 = unpk(tc.y), t2 = unpk(tc.z), t3 = unpk(tc.w);
        const float tv[8] = {t0.x, t0.y, t1.x, t1.y, t2.x, t2.y, t3.x, t3.y};
        const float iv[8] = {ic0.x, ic0.y, ic0.z, ic0.w, ic1.x, ic1.y, ic1.z, ic1.w};

        #pragma unroll
        for (int k = 0; k < 8; ++k) {
            const float wgt = fmaf(5.0f, fabsf(fmaf(win[k], inv, -tv[k])), 1.0f);
            aI += iv[k] * tv[k] * wgt;
            aA += iv[k] * wgt;
            aB += tv[k] * wgt;
        }

        // ---- apply vr advance from temps ----------------------------------
        if (j < 7) {
            #pragma unroll
            for (int q = 0; q < 4; ++q) {
                const float2 a0 = unpk(ua[q].x), a1 = unpk(ua[q].y),
                             a2 = unpk(ua[q].z), a3 = unpk(ua[q].w);
                const float2 s0 = unpk(us[q].x), s1 = unpk(us[q].y),
                             s2 = unpk(us[q].z), s3 = unpk(us[q].w);
                vr[0] += a0.x - s0.x; vr[1] += a0.y - s0.y;
                vr[2] += a1.x - s1.x; vr[3] += a1.y - s1.y;
                vr[4] += a2.x - s2.x; vr[5] += a2.y - s2.y;
                vr[6] += a3.x - s3.x; vr[7] += a3.y - s3.y;
            }
        }

        // ---- barrier A: all ring READS of this step complete (data-dep
        //      waits already consumed them) before anyone overwrites --------
        __builtin_amdgcn_sched_barrier(0);
        __builtin_amdgcn_s_barrier();
        __builtin_amdgcn_sched_barrier(0);

        // ---- publish prefetched row prow(j)=h+23 (loaded LAST iteration;
        //      compiler inserts counted vmcnt here = a full step of cover) --
        if (j < 7 && (h + 23) < H) {
            uint4 u;
            u.x = pack2(pc0.x, pc0.y); u.y = pack2(pc0.z, pc0.w);
            u.z = pack2(pc1.x, pc1.y); u.w = pack2(pc1.z, pc1.w);
            *(uint4*)&ring[wrap38(sl_h + 23) * 256 + ofs] = u;
        }
        // ---- barrier B: publish visible to all waves (lgkm only; global
        //      loads for the next step stay in flight) ----------------------
        asm volatile("s_waitcnt lgkmcnt(0)" ::: "memory");
        __builtin_amdgcn_sched_barrier(0);
        __builtin_amdgcn_s_barrier();
        __builtin_amdgcn_sched_barrier(0);

        // ---- rotate pipeline registers ------------------------------------
        pc0 = pn0; pc1 = pn1; ic0 = in0; ic1 = in1;
        sl_h = wrap38(sl_h + 4);
    }

    // wave reduction (64 lanes)
    #pragma unroll
    for (int off = 32; off > 0; off >>= 1) {
        aI += __shfl_down(aI, off, 64);
        aA += __shfl_down(aA, off, 64);
        aB += __shfl_down(aB, off, 64);
    }
    // cross-wave reduction reusing ring storage
    float* rf = (float*)ring;
    if (lane == 0) { rf[wv] = aI; rf[8 + wv] = aA; rf[16 + wv] = aB; }
    __syncthreads();
    if (tid == 0) {
        float4 o;
        o.x = rf[0] + rf[1] + rf[2] + rf[3];
        o.y = rf[8] + rf[9] + rf[10] + rf[11];
        o.z = rf[16] + rf[17] + rf[18] + rf[19];
        o.w = 0.f;
        partials[blk] = o;
    }
}

// ---------------------------------------------------------------------------
// Reduce NBLK (1024) partials + finalize. One block, 1024 threads (16 waves).
// ---------------------------------------------------------------------------
__global__ __launch_bounds__(1024) void reduce_kernel(const float4* __restrict__ partials,
                                                      float* __restrict__ out) {
    const int tid = threadIdx.x;
    const float4 v = partials[tid];          // exactly 1024 entries
    float aI = v.x, aA = v.y, aB = v.z;
    #pragma unroll
    for (int off = 32; off > 0; off >>= 1) {
        aI += __shfl_down(aI, off, 64);
        aA += __shfl_down(aA, off, 64);
        aB += __shfl_down(aB, off, 64);
    }
    __shared__ float s[3][16];
    const int wvx = tid >> 6, ln = tid & 63;
    if (ln == 0) { s[0][wvx] = aI; s[1][wvx] = aA; s[2][wvx] = aB; }
    __syncthreads();
    if (tid == 0) {
        float I = 0.f, A = 0.f, Bv = 0.f;
        #pragma unroll
        for (int k = 0; k < 16; ++k) { I += s[0][k]; A += s[1][k]; Bv += s[2][k]; }
        out[0] = 1.0f - (2.0f * I + 1.0f) / (A + Bv + 1.0f);
    }
}

extern "C" void kernel_launch(void* const* d_in, const int* in_sizes, int n_in,
                              void* d_out, int out_size, void* d_ws, size_t ws_size,
                              hipStream_t stream) {
    const float* inp = (const float*)d_in[0];   // "input"
    const float* tgt = (const float*)d_in[1];   // "target"
    float* out = (float*)d_out;

    // workspace: [0, NBLK*16) per-block partials (float4); written before read.
    float4* partials = (float4*)d_ws;

    fused_kernel<<<NBLK, 256, 0, stream>>>(tgt, inp, partials);
    reduce_kernel<<<1, 1024, 0, stream>>>(partials, out);
}